// Round 10
// baseline (1519.756 us; speedup 1.0000x reference)
//
#include <hip/hip_runtime.h>
#include <hip/hip_fp16.h>

#define T 4096
#define EP 8                      // steps per barrier epoch
#define RING 32                   // LDS ring depth (disjoint writer/reader mod 32)
#define NEP (T / EP + 2)          // 514 epochs: pipeline depth 2 epochs

typedef _Float16 h2v __attribute__((ext_vector_type(2)));

// tanh(x) = 1 - 2/(exp(2x)+1). Branch-free, ~1e-6 err.
__device__ __forceinline__ float fast_tanh(float x) {
    float e = __expf(2.0f * x);
    float r = __builtin_amdgcn_rcpf(e + 1.0f);
    return fmaf(-2.0f, r, 1.0f);
}

// 16-scalar residency anchors (once per epoch; near-zero cost).
#define ANCHOR16(a, b) asm volatile("" : \
    "+v"((a)[(b)+0]),  "+v"((a)[(b)+1]),  "+v"((a)[(b)+2]),  "+v"((a)[(b)+3]),  \
    "+v"((a)[(b)+4]),  "+v"((a)[(b)+5]),  "+v"((a)[(b)+6]),  "+v"((a)[(b)+7]),  \
    "+v"((a)[(b)+8]),  "+v"((a)[(b)+9]),  "+v"((a)[(b)+10]), "+v"((a)[(b)+11]), \
    "+v"((a)[(b)+12]), "+v"((a)[(b)+13]), "+v"((a)[(b)+14]), "+v"((a)[(b)+15]))
#define ANCHOR64(a) do { ANCHOR16(a, 0); ANCHOR16(a, 16); \
                         ANCHOR16(a, 32); ANCHOR16(a, 48); } while (0)

// ---------------------------------------------------------------------------
// R10: f16 pair-dot rotation decomposition.
// R9 post-mortem: clock theory dead (heaters null). Ledger pins DPP-class ops
// at ~4 cyc; R7's 64/step = the floor term. R10 halves broadcast-class ops:
// pack h as f16 pairs (h[i],h[i^16]) -> one DPP row_ror rotates BOTH halves,
// one v_dot2_f32_f16 consumes both products (f32 accumulate).
//   prep: b16=bpermute(h); pkA=cvt_pk(h,b16); pkB=bpermute(pkA, lane^32)
//   inner: 30 update_dpp + 32 fdot2 (vs 64 fmac_dpp)
// Weights: f16-rn pairs, R6-verified sigma(r) permutation:
//   w01[r] = (W[i][s], W[i][s^16]), w23[r] = (W[i][s^32], W[i][s^48]),
//   s = (i&48)|((i+off(r))&15), off per probed row_ror direction.
// NUMERICS: W,h quantized to f16 in the recurrence. Contractive map
// (rho~0.58) bounds steady-state h error ~2e-4; expected final absmax
// ~1e-4..5e-4 (first deliberately-nonzero round). Revert to R7 if it fails.
// ---------------------------------------------------------------------------
__device__ __forceinline__ float fdot2u(unsigned a, unsigned b, float c) {
    return __builtin_amdgcn_fdot2(__builtin_bit_cast(h2v, a),
                                  __builtin_bit_cast(h2v, b), c, false);
}

__device__ __forceinline__ unsigned pack_rn(float a, float b) {   // cold path
    unsigned lo = (unsigned)__half_as_ushort(__float2half_rn(a));
    unsigned hi = (unsigned)__half_as_ushort(__float2half_rn(b));
    return lo | (hi << 16);
}

__device__ __forceinline__ unsigned pack_rtz(float a, float b) {  // hot path, 1 inst
    return __builtin_bit_cast(unsigned, __builtin_amdgcn_cvt_pkrtz(a, b));
}

#define DOTROT(acc, pk, w, R) \
    (acc) = fdot2u((unsigned)__builtin_amdgcn_update_dpp( \
                0, (int)(pk), 0x120 + (R), 0xF, 0xF, false), (w), (acc))

// 16 rotations of one packed source: r=0 direct, r=1..15 via DPP. acc = r&3.
#define DOTBLOCK(pk, w) do { \
    a0 = fdot2u((pk), (w)[0], a0); \
    DOTROT(a1,(pk),(w)[1], 1);  DOTROT(a2,(pk),(w)[2], 2);  DOTROT(a3,(pk),(w)[3], 3); \
    DOTROT(a0,(pk),(w)[4], 4);  DOTROT(a1,(pk),(w)[5], 5);  DOTROT(a2,(pk),(w)[6], 6); \
    DOTROT(a3,(pk),(w)[7], 7);  DOTROT(a0,(pk),(w)[8], 8);  DOTROT(a1,(pk),(w)[9], 9); \
    DOTROT(a2,(pk),(w)[10],10); DOTROT(a3,(pk),(w)[11],11); DOTROT(a0,(pk),(w)[12],12); \
    DOTROT(a1,(pk),(w)[13],13); DOTROT(a2,(pk),(w)[14],14); DOTROT(a3,(pk),(w)[15],15); \
} while (0)

// One recurrence step: tanh(init + W@h). pkB's bpermute latency hides under
// the first DOTBLOCK. Builtins only -> compiler handles all DPP hazards.
__device__ __forceinline__ float rnn_step_dot(const unsigned (&w01)[16],
                                              const unsigned (&w23)[16],
                                              float init, float hp,
                                              int a16, int a32) {
    const int  b16 = __builtin_amdgcn_ds_bpermute(a16, __float_as_int(hp));
    const unsigned pkA = pack_rtz(hp, __int_as_float(b16));      // (h[i],h[i^16])
    const unsigned pkB = (unsigned)__builtin_amdgcn_ds_bpermute(a32, (int)pkA);
    float a0 = init, a1 = 0.f, a2 = 0.f, a3 = 0.f;
    DOTBLOCK(pkA, w01);
    DOTBLOCK(pkB, w23);                                          // (h[i^32],h[i^48])
    return fast_tanh((a0 + a1) + (a2 + a3));
}

// Pre-permuted f16 weight pairs (sigma(r) mapping verified in R6/R7, absmax 0).
__device__ __forceinline__ void load_wdot(const float* __restrict__ W, int lane,
                                          bool dirplus,
                                          unsigned (&w01)[16], unsigned (&w23)[16]) {
#pragma unroll
    for (int r = 0; r < 16; ++r) {
        const int lowoff = dirplus ? r : ((16 - r) & 15);
        const int j = (lane & 48) | ((lane + lowoff) & 15);
        w01[r] = pack_rn(W[lane * 64 + j],        W[lane * 64 + (j ^ 16)]);
        w23[r] = pack_rn(W[lane * 64 + (j ^ 32)], W[lane * 64 + (j ^ 48)]);
    }
}

// ---------------------------------------------------------------------------
// prep: pre[s][t][i] = b_ih0[i] + b_hh0[i] + sum_d W_ih0[i][d] * in[0,t,d]
// Only batch element 0 of x / y matters (reference uses e[0], o[0] only).
// ---------------------------------------------------------------------------
__global__ void prep_kernel(const float* __restrict__ x, const float* __restrict__ y,
                            const float* __restrict__ eW, const float* __restrict__ ebi,
                            const float* __restrict__ ebh,
                            const float* __restrict__ oW, const float* __restrict__ obi,
                            const float* __restrict__ obh,
                            float* __restrict__ pre)
{
    int idx = blockIdx.x * blockDim.x + threadIdx.x;   // 2*T*64 threads
    int i = idx & 63;
    int t = (idx >> 6) & (T - 1);
    int s = idx >> 18;
    const float* in = s ? y : x;          // batch 0 = first T*3 floats
    const float* W  = s ? oW : eW;        // [64][3]
    const float* bi = s ? obi : ebi;
    const float* bh = s ? obh : ebh;
    float v = bi[i] + bh[i]
            + W[i*3+0]*in[t*3+0] + W[i*3+1]*in[t*3+1] + W[i*3+2]*in[t*3+2];
    pre[idx] = v;
}

// ---------------------------------------------------------------------------
// seq: grid=2 (one block per RNN), 4 specialized waves, barrier per EP epoch.
//   wave0 @ epoch k: h0[t] = tanh(p[t] + Whh0@h0[t-1]), t in [8k, 8k+8)
//   wave1/wave2 @ epoch k: q[t] = b1 + Wih1@h0[t], t-split halves of [8k-8,8k)
//   wave3 @ epoch k: h1[t] = tanh(q[t] + Whh1@h1[t-1]), t in [8k-16, 8k-8)
// Ring safety (mod 32): cross-wave readers >=1 barrier behind writers.
// ---------------------------------------------------------------------------
__global__ __launch_bounds__(256, 1) void seq_kernel(
    const float* __restrict__ pre,            // [2][T][64]
    const float* __restrict__ eWhh0, const float* __restrict__ eWih1,
    const float* __restrict__ eWhh1, const float* __restrict__ ebih1,
    const float* __restrict__ ebhh1,
    const float* __restrict__ oWhh0, const float* __restrict__ oWih1,
    const float* __restrict__ oWhh1, const float* __restrict__ obih1,
    const float* __restrict__ obhh1,
    float* __restrict__ hlast)                // [2][64]
{
    const int s    = blockIdx.x;
    const int wv   = threadIdx.x >> 6;
    const int lane = threadIdx.x & 63;

    __shared__ __align__(16) float h0ring[RING][64];
    __shared__ __align__(16) float qring[RING][64];

    const float* p = pre + s * T * 64;

    // Probe the hardware row_ror direction (wave-uniform result; R6-verified).
    const int got = __builtin_amdgcn_update_dpp(0, lane, 0x121, 0xF, 0xF, false);
    const bool dirplus = ((got & 15) == ((lane + 1) & 15));
    // bpermute byte-addresses
    const int a16 = (lane ^ 16) << 2;
    const int a32 = (lane ^ 32) << 2;

    if (wv == 0) {
        // ---------- layer-0 recurrence wave ----------
        const float* Whh0 = s ? oWhh0 : eWhh0;
        unsigned w01[16], w23[16];
        load_wdot(Whh0, lane, dirplus, w01, w23);

        float hp = 0.f;                        // h0[t-1]
        float pc[EP], pn[EP];
#pragma unroll
        for (int i = 0; i < EP; ++i) pc[i] = p[i * 64 + lane];

        for (int k = 0; k < NEP; ++k) {
            ANCHOR16(w01, 0); ANCHOR16(w23, 0);    // keep weight pairs resident
            const int base = k * EP;
            // prefetch next epoch's p (consumed next epoch -> latency hidden)
#pragma unroll
            for (int i = 0; i < EP; ++i) {
                int t = base + EP + i;
                pn[i] = (t < T) ? p[t * 64 + lane] : 0.f;
            }
            if (base < T) {                    // wave-uniform scalar branch
#pragma unroll
                for (int i = 0; i < EP; ++i) {
                    hp = rnn_step_dot(w01, w23, pc[i], hp, a16, a32);
                    h0ring[(base + i) & (RING - 1)][lane] = hp;   // publish
                }
            }
#pragma unroll
            for (int i = 0; i < EP; ++i) pc[i] = pn[i];
            __syncthreads();
        }
    } else if (wv <= 2) {
        // ---------- helper waves: layer-1 input projection, t-split (f32) ----
        const float* Wih1 = s ? oWih1 : eWih1;
        const float  b1   = s ? (obih1[lane] + obhh1[lane])
                              : (ebih1[lane] + ebhh1[lane]);
        float wi[64];
#pragma unroll
        for (int j = 0; j < 64; ++j) wi[j] = Wih1[lane * 64 + j];

        const int i0 = (wv - 1) * (EP / 2);    // wave1: t 0..3, wave2: t 4..7

        for (int k = 0; k < NEP; ++k) {
            ANCHOR64(wi);
            const int base = k * EP - EP;
            if (base >= 0 && base < T) {
#pragma unroll
                for (int i = 0; i < EP / 2; ++i) {
                    const int t = base + i0 + i;
                    const float4* hv = (const float4*)h0ring[t & (RING - 1)];
                    float q[4] = { b1, 0.f, 0.f, 0.f };
#pragma unroll
                    for (int j4 = 0; j4 < 16; ++j4) {
                        float4 u = hv[j4];
                        q[0] = fmaf(wi[4*j4+0], u.x, q[0]);
                        q[1] = fmaf(wi[4*j4+1], u.y, q[1]);
                        q[2] = fmaf(wi[4*j4+2], u.z, q[2]);
                        q[3] = fmaf(wi[4*j4+3], u.w, q[3]);
                    }
                    qring[t & (RING - 1)][lane] = (q[0] + q[1]) + (q[2] + q[3]);
                }
            }
            __syncthreads();
        }
    } else {
        // ---------- layer-1 recurrence wave ----------
        const float* Whh1 = s ? oWhh1 : eWhh1;
        unsigned w01[16], w23[16];
        load_wdot(Whh1, lane, dirplus, w01, w23);

        float hp = 0.f;                        // h1[t-1]
        for (int k = 0; k < NEP; ++k) {
            ANCHOR16(w01, 0); ANCHOR16(w23, 0);
            const int base = k * EP - 2 * EP;
            if (base >= 0) {                   // base+EP-1 <= T-1 by construction
                float qb[EP];
#pragma unroll
                for (int i = 0; i < EP; ++i)   // all written >=1 epoch ago
                    qb[i] = qring[(base + i) & (RING - 1)][lane];
#pragma unroll
                for (int i = 0; i < EP; ++i)
                    hp = rnn_step_dot(w01, w23, qb[i], hp, a16, a32);
            }
            __syncthreads();
        }
        hlast[s * 64 + lane] = hp;             // h1[T-1]
    }
}

// ---------------------------------------------------------------------------
// head: e0 = fce_w@hx + fce_b ; o0 = fco_w@hy + fco_b ; zz=[e0,o0,z];
//       h = relu(fc1_w@zz + fc1_b) ; out = fc2_w@h + fc2_b
// ---------------------------------------------------------------------------
__global__ void head_kernel(const float* __restrict__ hlast,   // [2][64]
                            const float* __restrict__ z,
                            const float* __restrict__ fce_w, const float* __restrict__ fce_b,
                            const float* __restrict__ fco_w, const float* __restrict__ fco_b,
                            const float* __restrict__ fc1_w, const float* __restrict__ fc1_b,
                            const float* __restrict__ fc2_w, const float* __restrict__ fc2_b,
                            float* __restrict__ out)            // [5]
{
    const int lane = threadIdx.x;   // 64 threads
    __shared__ float zz[9];
    __shared__ float hh[64];

    if (lane < 2) {
        float sacc = fce_b[lane];
        for (int j = 0; j < 64; ++j) sacc += fce_w[lane * 64 + j] * hlast[j];
        zz[lane] = sacc;
    } else if (lane < 4) {
        int r = lane - 2;
        float sacc = fco_b[r];
        for (int j = 0; j < 64; ++j) sacc += fco_w[r * 64 + j] * hlast[64 + j];
        zz[lane] = sacc;
    } else if (lane < 9) {
        zz[lane] = z[lane - 4];
    }
    __syncthreads();

    float sacc = fc1_b[lane];
#pragma unroll
    for (int j = 0; j < 9; ++j) sacc += fc1_w[lane * 9 + j] * zz[j];
    hh[lane] = fmaxf(sacc, 0.f);
    __syncthreads();

    if (lane < 5) {
        float o = fc2_b[lane];
        for (int i = 0; i < 64; ++i) o += fc2_w[lane * 64 + i] * hh[i];
        out[lane] = o;
    }
}

// ---------------------------------------------------------------------------
extern "C" void kernel_launch(void* const* d_in, const int* in_sizes, int n_in,
                              void* d_out, int out_size, void* d_ws, size_t ws_size,
                              hipStream_t stream)
{
    const float* x      = (const float*)d_in[0];
    const float* y      = (const float*)d_in[1];
    const float* z      = (const float*)d_in[2];
    const float* e_Wih0 = (const float*)d_in[3];
    const float* e_Whh0 = (const float*)d_in[4];
    const float* e_bih0 = (const float*)d_in[5];
    const float* e_bhh0 = (const float*)d_in[6];
    const float* e_Wih1 = (const float*)d_in[7];
    const float* e_Whh1 = (const float*)d_in[8];
    const float* e_bih1 = (const float*)d_in[9];
    const float* e_bhh1 = (const float*)d_in[10];
    const float* o_Wih0 = (const float*)d_in[11];
    const float* o_Whh0 = (const float*)d_in[12];
    const float* o_bih0 = (const float*)d_in[13];
    const float* o_bhh0 = (const float*)d_in[14];
    const float* o_Wih1 = (const float*)d_in[15];
    const float* o_Whh1 = (const float*)d_in[16];
    const float* o_bih1 = (const float*)d_in[17];
    const float* o_bhh1 = (const float*)d_in[18];
    const float* fce_w  = (const float*)d_in[19];
    const float* fce_b  = (const float*)d_in[20];
    const float* fco_w  = (const float*)d_in[21];
    const float* fco_b  = (const float*)d_in[22];
    const float* fc1_w  = (const float*)d_in[23];
    const float* fc1_b  = (const float*)d_in[24];
    const float* fc2_w  = (const float*)d_in[25];
    const float* fc2_b  = (const float*)d_in[26];

    float* pre   = (float*)d_ws;            // 2*T*64 floats = 2 MB
    float* hlast = pre + 2 * T * 64;        // 128 floats
    float* out   = (float*)d_out;

    prep_kernel<<<(2 * T * 64) / 256, 256, 0, stream>>>(
        x, y, e_Wih0, e_bih0, e_bhh0, o_Wih0, o_bih0, o_bhh0, pre);

    seq_kernel<<<2, 256, 0, stream>>>(
        pre,
        e_Whh0, e_Wih1, e_Whh1, e_bih1, e_bhh1,
        o_Whh0, o_Wih1, o_Whh1, o_bih1, o_bhh1,
        hlast);

    head_kernel<<<1, 64, 0, stream>>>(
        hlast, z, fce_w, fce_b, fco_w, fco_b, fc1_w, fc1_b, fc2_w, fc2_b, out);
}

// Round 11
// 1465.367 us; speedup vs baseline: 1.0371x; 1.0371x over previous
//
#include <hip/hip_runtime.h>
#include <hip/hip_fp16.h>

#define T 4096
#define EP 8                      // steps per barrier epoch
#define RING 32                   // LDS ring depth (disjoint writer/reader mod 32)
#define NEP (T / EP + 2)          // 514 epochs: pipeline depth 2 epochs

typedef _Float16 f16x8 __attribute__((ext_vector_type(8)));
typedef _Float16 f16x2 __attribute__((ext_vector_type(2)));
typedef float    f32x4 __attribute__((ext_vector_type(4)));
typedef unsigned long long u64;

// tanh(x) = 1 - 2/(exp(2x)+1). Branch-free, ~1e-6 err.
__device__ __forceinline__ float fast_tanh(float x) {
    float e = __expf(2.0f * x);
    float r = __builtin_amdgcn_rcpf(e + 1.0f);
    return fmaf(-2.0f, r, 1.0f);
}

// 16-scalar residency anchors (fallback path only).
#define ANCHOR16(a, b) asm volatile("" : \
    "+v"((a)[(b)+0]),  "+v"((a)[(b)+1]),  "+v"((a)[(b)+2]),  "+v"((a)[(b)+3]),  \
    "+v"((a)[(b)+4]),  "+v"((a)[(b)+5]),  "+v"((a)[(b)+6]),  "+v"((a)[(b)+7]),  \
    "+v"((a)[(b)+8]),  "+v"((a)[(b)+9]),  "+v"((a)[(b)+10]), "+v"((a)[(b)+11]), \
    "+v"((a)[(b)+12]), "+v"((a)[(b)+13]), "+v"((a)[(b)+14]), "+v"((a)[(b)+15]))
#define ANCHOR64(a) do { ANCHOR16(a, 0); ANCHOR16(a, 16); \
                         ANCHOR16(a, 32); ANCHOR16(a, 48); } while (0)

// ===========================================================================
// R7 fallback machinery (verified absmax 0.0, 988 us) — kept verbatim.
// ===========================================================================
#define ROTF(acc, v, w, R) \
    asm("v_fmac_f32_dpp %0, %1, %2 row_ror:" #R " row_mask:0xf bank_mask:0xf" \
        : "+v"(acc) : "v"(v), "v"(w))
#define MOVNOP(dst, src) \
    asm("v_mov_b32 %0, %1\n\ts_nop 1" : "=v"(dst) : "v"(src))
#define KBLOCK(v, wd, B) do { \
    a0 = fmaf((v), (wd)[(B) + 0], a0); \
    ROTF(a1, (v), (wd)[(B) + 1],  1);  ROTF(a2, (v), (wd)[(B) + 2],  2); \
    ROTF(a3, (v), (wd)[(B) + 3],  3);  ROTF(a0, (v), (wd)[(B) + 4],  4); \
    ROTF(a1, (v), (wd)[(B) + 5],  5);  ROTF(a2, (v), (wd)[(B) + 6],  6); \
    ROTF(a3, (v), (wd)[(B) + 7],  7);  ROTF(a0, (v), (wd)[(B) + 8],  8); \
    ROTF(a1, (v), (wd)[(B) + 9],  9);  ROTF(a2, (v), (wd)[(B) +10], 10); \
    ROTF(a3, (v), (wd)[(B) +11], 11);  ROTF(a0, (v), (wd)[(B) +12], 12); \
    ROTF(a1, (v), (wd)[(B) +13], 13);  ROTF(a2, (v), (wd)[(B) +14], 14); \
    ROTF(a3, (v), (wd)[(B) +15], 15); \
} while (0)

__device__ __forceinline__ float rnn_step_dpp(const float (&wd)[64], float init, float hp,
                                              int a16, int a32, int a48) {
    const int hb = __float_as_int(hp);
    const int b1i = __builtin_amdgcn_ds_bpermute(a16, hb);   // h[i^16]
    const int b2i = __builtin_amdgcn_ds_bpermute(a32, hb);   // h[i^32]
    const int b3i = __builtin_amdgcn_ds_bpermute(a48, hb);   // h[i^48]
    float hpD; MOVNOP(hpD, hp);
    float a0 = init, a1 = 0.f, a2 = 0.f, a3 = 0.f;
    KBLOCK(hpD, wd, 0);
    float v1; MOVNOP(v1, __int_as_float(b1i)); KBLOCK(v1, wd, 16);
    float v2; MOVNOP(v2, __int_as_float(b2i)); KBLOCK(v2, wd, 32);
    float v3; MOVNOP(v3, __int_as_float(b3i)); KBLOCK(v3, wd, 48);
    return fast_tanh((a0 + a1) + (a2 + a3));
}

__device__ __forceinline__ void load_wdpp(const float* __restrict__ W, int lane,
                                          bool dirplus, float (&wd)[64]) {
#pragma unroll
    for (int m = 0; m < 64; ++m) {
        const int k = m >> 4, r = m & 15;
        const int lowoff = dirplus ? r : ((16 - r) & 15);
        const int j = ((lane & 48) | ((lane + lowoff) & 15)) ^ (k << 4);
        wd[m] = W[lane * 64 + j];
    }
}

// ===========================================================================
// R11: MFMA recurrence.
// Decomposition: out[64] = W(64x64) @ h(64) via 4 row-blocks x 2 K-chunks of
// mfma_f32_16x16x32_f16, with h REPLICATED across B columns. Layouts:
//   D/C (HW-verified m89): col = lo, row = 4*hi + reg           (lo=lane&15, hi=lane>>4)
//   A (hypothesis, from tr_b16 m156/m162): row = lo, k = kmap(e) = 16*(e>>2)+4*hi+(e&3)
//   B (hypothesis):                        col = lo, k = kmap(e)
// CLOSED LOOP: lane holds D values out[16b+4*hi+r]; next-step B fragment
// chunk ch elem e needs h[32ch + kmap(e)] = out[16*(2ch+(e>>2)) + 4*hi + (e&3)]
// -> lane-local! Only the distributed tanh needs cross-col movement.
// Distributed tanh: col-group myb=lo&3 handles block myb (4 tanh/lane); the
// other 3 blocks' packed f16 words arrive via DPP row_ror 1..3 + mask-selects.
// A two-step runtime probe verifies the layout hypothesis end-to-end
// (mfma+repack vs direct f32 reference); failure -> R7 fallback (bit-identical
// to the 988us kernel).
// ===========================================================================
#define MFMA16(a, b, c) __builtin_amdgcn_mfma_f32_16x16x32_f16((a), (b), (c), 0, 0, 0)

#define DPPROR(dst, src, R) \
    dst = (unsigned)__builtin_amdgcn_update_dpp(0, (int)(src), 0x120 + (R), 0xF, 0xF, false)

// 1-instruction select with a precomputed 64-bit lane mask: d = m ? s1 : s0
__device__ __forceinline__ unsigned selmask(unsigned s0, unsigned s1, u64 m) {
    unsigned d;
    asm("v_cndmask_b32 %0, %1, %2, %3" : "=v"(d) : "v"(s0), "v"(s1), "s"(m));
    return d;
}
__device__ __forceinline__ float selmaskf(float s0, float s1, u64 m) {
    float d;
    asm("v_cndmask_b32 %0, %1, %2, %3" : "=v"(d) : "v"(s0), "v"(s1), "s"(m));
    return d;
}

struct SelMasks {
    u64 mb1, mb3, mbhi;        // presel: pick own block from d[0..3] by myb
    u64 m0[4], m1[4], m2[4];   // repack: source-of-block-b masks (own/ror1/ror2)
};

__device__ __forceinline__ void build_masks(int lo, bool dirplus, SelMasks &M) {
    const int myb = lo & 3;
    const int rb1 = (dirplus ? (lo + 1) : (lo + 15)) & 3;   // block received via ror1
    const int rb2 = (dirplus ? (lo + 2) : (lo + 14)) & 3;   // via ror2
    M.mb1  = __ballot(myb == 1);
    M.mb3  = __ballot(myb == 3);
    M.mbhi = __ballot(myb >= 2);
#pragma unroll
    for (int b = 0; b < 4; ++b) {
        M.m0[b] = __ballot(myb == b);
        M.m1[b] = __ballot(rb1 == b);
        M.m2[b] = __ballot(rb2 == b);
    }
}

// A fragments: afrag[b][ch][e] = f16( W[16b + lo][32ch + kmap(e)] )
__device__ __forceinline__ void load_afrag(const float* __restrict__ W, int lo, int hi,
                                           f16x8 (&A)[4][2]) {
#pragma unroll
    for (int b = 0; b < 4; ++b)
#pragma unroll
        for (int ch = 0; ch < 2; ++ch) {
            f16x8 v;
#pragma unroll
            for (int e = 0; e < 8; ++e) {
                const int k = 32 * ch + 16 * (e >> 2) + 4 * hi + (e & 3);
                v[e] = (_Float16)W[(16 * b + lo) * 64 + k];
            }
            A[b][ch] = v;
        }
}

// 8 MFMA: d[b] = W[16b.., 0:64] @ h + cin[b]
__device__ __forceinline__ void mfma8(const f16x8 (&A)[4][2], f16x8 b0, f16x8 b1,
                                      const f32x4 (&cin)[4], f32x4 (&d)[4]) {
#pragma unroll
    for (int b = 0; b < 4; ++b) d[b] = MFMA16(A[b][0], b0, cin[b]);
#pragma unroll
    for (int b = 0; b < 4; ++b) d[b] = MFMA16(A[b][1], b1, d[b]);
}

// Distributed tanh + fragment rebuild. thOut = own block's tanh'd f32x4
// (lane lo<4 holds block lo -> used for f32 publish).
__device__ __forceinline__ void repack(const f32x4 (&d)[4], const SelMasks &M,
                                       f16x8 &bf0, f16x8 &bf1, f32x4 &thOut) {
    float th[4];
#pragma unroll
    for (int r = 0; r < 4; ++r) {
        float a = selmaskf(d[0][r], d[1][r], M.mb1);
        float b = selmaskf(d[2][r], d[3][r], M.mb3);
        th[r] = fast_tanh(selmaskf(a, b, M.mbhi));
    }
    thOut = (f32x4){ th[0], th[1], th[2], th[3] };
    const unsigned w0 = __builtin_bit_cast(unsigned, __builtin_amdgcn_cvt_pkrtz(th[0], th[1]));
    const unsigned w1 = __builtin_bit_cast(unsigned, __builtin_amdgcn_cvt_pkrtz(th[2], th[3]));
    unsigned r1w0, r1w1, r2w0, r2w1, r3w0, r3w1;
    DPPROR(r1w0, w0, 1); DPPROR(r1w1, w1, 1);
    DPPROR(r2w0, w0, 2); DPPROR(r2w1, w1, 2);
    DPPROR(r3w0, w0, 3); DPPROR(r3w1, w1, 3);
    unsigned gw0[4], gw1[4];
#pragma unroll
    for (int b = 0; b < 4; ++b) {
        unsigned t = selmask(r3w0, r2w0, M.m2[b]);
        t = selmask(t, r1w0, M.m1[b]);
        gw0[b] = selmask(t, w0, M.m0[b]);
        unsigned u = selmask(r3w1, r2w1, M.m2[b]);
        u = selmask(u, r1w1, M.m1[b]);
        gw1[b] = selmask(u, w1, M.m0[b]);
    }
    const uint4 q0 = { gw0[0], gw1[0], gw0[1], gw1[1] };   // blocks 0,1 -> k 0..31
    const uint4 q1 = { gw0[2], gw1[2], gw0[3], gw1[3] };   // blocks 2,3 -> k 32..63
    bf0 = __builtin_bit_cast(f16x8, q0);
    bf1 = __builtin_bit_cast(f16x8, q1);
}

__device__ __forceinline__ float probe_h(int j) {
    return (float)((j * 37 + 11) & 63) * 0.015625f - 0.5f;   // distinct, in [-0.5, 0.48]
}

// Two-step end-to-end probe: (1) mfma8 vs direct W@hT; (2) repack+mfma8 vs
// direct W@tanh(W@hT). Covers layout hypothesis AND repack logic. scr = 64-float
// LDS scratch private to this wave. Wave-uniform result.
__device__ bool probe_mfma(const float* __restrict__ W, int lane, int lo, int hi,
                           const f16x8 (&A)[4][2], const SelMasks &M,
                           volatile float* scr) {
    float ref = 0.f;
#pragma unroll 1
    for (int j = 0; j < 64; ++j) ref = fmaf(W[lane * 64 + j], probe_h(j), ref);
    scr[lane] = ref;
    asm volatile("s_waitcnt lgkmcnt(0)" ::: "memory");

    f16x8 b0, b1;
#pragma unroll
    for (int e = 0; e < 8; ++e) {
        const int k = 16 * (e >> 2) + 4 * hi + (e & 3);
        b0[e] = (_Float16)probe_h(k);
        b1[e] = (_Float16)probe_h(32 + k);
    }
    const f32x4 z = { 0.f, 0.f, 0.f, 0.f };
    const f32x4 cz[4] = { z, z, z, z };
    f32x4 d[4];
    mfma8(A, b0, b1, cz, d);
    bool ok = true;
#pragma unroll
    for (int b = 0; b < 4; ++b)
#pragma unroll
        for (int r = 0; r < 4; ++r)
            ok = ok && (fabsf(d[b][r] - scr[16 * b + 4 * hi + r]) < 0.05f);

    // stage 2: repack -> next B; reference = W @ tanh(ref)
    asm volatile("s_waitcnt lgkmcnt(0)" ::: "memory");
    scr[lane] = fast_tanh(ref);
    asm volatile("s_waitcnt lgkmcnt(0)" ::: "memory");
    float ref2 = 0.f;
#pragma unroll 1
    for (int j = 0; j < 64; ++j) ref2 = fmaf(W[lane * 64 + j], scr[j], ref2);
    asm volatile("s_waitcnt lgkmcnt(0)" ::: "memory");
    scr[lane] = ref2;
    asm volatile("s_waitcnt lgkmcnt(0)" ::: "memory");

    f32x4 th;
    repack(d, M, b0, b1, th);
    f32x4 d2[4];
    mfma8(A, b0, b1, cz, d2);
#pragma unroll
    for (int b = 0; b < 4; ++b)
#pragma unroll
        for (int r = 0; r < 4; ++r)
            ok = ok && (fabsf(d2[b][r] - scr[16 * b + 4 * hi + r]) < 0.10f);
    return __all(ok) != 0;
}

__device__ __forceinline__ void loadP(const float* __restrict__ p, int t, int hi,
                                      f32x4 (&c)[4]) {
#pragma unroll
    for (int b = 0; b < 4; ++b)
        c[b] = *(const f32x4*)(p + t * 64 + 16 * b + 4 * hi);
}

// ---------------------------------------------------------------------------
// prep: pre[s][t][i] = b_ih0[i] + b_hh0[i] + sum_d W_ih0[i][d] * in[0,t,d]
// ---------------------------------------------------------------------------
__global__ void prep_kernel(const float* __restrict__ x, const float* __restrict__ y,
                            const float* __restrict__ eW, const float* __restrict__ ebi,
                            const float* __restrict__ ebh,
                            const float* __restrict__ oW, const float* __restrict__ obi,
                            const float* __restrict__ obh,
                            float* __restrict__ pre)
{
    int idx = blockIdx.x * blockDim.x + threadIdx.x;   // 2*T*64 threads
    int i = idx & 63;
    int t = (idx >> 6) & (T - 1);
    int s = idx >> 18;
    const float* in = s ? y : x;          // batch 0 = first T*3 floats
    const float* W  = s ? oW : eW;        // [64][3]
    const float* bi = s ? obi : ebi;
    const float* bh = s ? obh : ebh;
    float v = bi[i] + bh[i]
            + W[i*3+0]*in[t*3+0] + W[i*3+1]*in[t*3+1] + W[i*3+2]*in[t*3+2];
    pre[idx] = v;
}

// ---------------------------------------------------------------------------
// seq: grid=2 (one block per RNN), 4 specialized waves, barrier per EP epoch.
//   wave0 @ epoch k: h0[t], t in [8k, 8k+8)          (MFMA path or R7 fallback)
//   wave1/wave2 @ epoch k: q[t] = b1 + Wih1@h0[t], t-split halves of [8k-8,8k)
//   wave3 @ epoch k: h1[t], t in [8k-16, 8k-8)       (MFMA path or R7 fallback)
// Ring safety (mod 32): cross-wave readers >=1 barrier behind writers.
// MFMA publish: lanes lo<4 hold block lo -> ds_write_b128 of 4 f32 covers all
// 64 indices (16*lo + 4*hi + r). Helpers consume full-precision f32 as before.
// ---------------------------------------------------------------------------
__global__ __launch_bounds__(256, 1) void seq_kernel(
    const float* __restrict__ pre,            // [2][T][64]
    const float* __restrict__ eWhh0, const float* __restrict__ eWih1,
    const float* __restrict__ eWhh1, const float* __restrict__ ebih1,
    const float* __restrict__ ebhh1,
    const float* __restrict__ oWhh0, const float* __restrict__ oWih1,
    const float* __restrict__ oWhh1, const float* __restrict__ obih1,
    const float* __restrict__ obhh1,
    float* __restrict__ hlast)                // [2][64]
{
    const int s    = blockIdx.x;
    const int wv   = threadIdx.x >> 6;
    const int lane = threadIdx.x & 63;
    const int lo   = lane & 15;
    const int hi   = lane >> 4;

    __shared__ __align__(16) float h0ring[RING][64];
    __shared__ __align__(16) float qring[RING][64];
    __shared__ __align__(16) float pscr[2][64];      // probe scratch per rec-wave

    const float* p = pre + s * T * 64;

    // Probe the hardware row_ror direction (wave-uniform; R6-verified method).
    const int got = __builtin_amdgcn_update_dpp(0, lane, 0x121, 0xF, 0xF, false);
    const bool dirplus = ((got & 15) == ((lane + 1) & 15));
    // bpermute byte-addresses (fallback path)
    const int a16 = (lane ^ 16) << 2;
    const int a32 = (lane ^ 32) << 2;
    const int a48 = (lane ^ 48) << 2;

    if (wv == 0) {
        // ---------- layer-0 recurrence wave ----------
        const float* Whh0 = s ? oWhh0 : eWhh0;
        SelMasks M; build_masks(lo, dirplus, M);
        f16x8 A[4][2];
        load_afrag(Whh0, lo, hi, A);
        const bool useMfma = probe_mfma(Whh0, lane, lo, hi, A, M, pscr[0]);

        if (useMfma) {
            f16x8 bf0 = {}, bf1 = {};              // h[-1] = 0
            f32x4 pf[2][4];
            loadP(p, 0, hi, pf[0]);
            loadP(p, 1, hi, pf[1]);
            for (int k = 0; k < NEP; ++k) {
                const int base = k * EP;
                if (base < T) {
#pragma unroll
                    for (int i = 0; i < EP; ++i) {
                        const int t = base + i;
                        f32x4 d[4];
                        mfma8(A, bf0, bf1, pf[i & 1], d);
                        int tn = t + 2; if (tn > T - 1) tn = T - 1;
                        loadP(p, tn, hi, pf[i & 1]);          // consumed in 2 steps
                        f32x4 th;
                        repack(d, M, bf0, bf1, th);
                        if (lo < 4)
                            *(f32x4*)&h0ring[t & (RING - 1)][16 * lo + 4 * hi] = th;
                    }
                }
                __syncthreads();
            }
        } else {
            // -------- R7 fallback (bit-identical to the 988us kernel) --------
            float wd[64];
            load_wdpp(Whh0, lane, dirplus, wd);
            float hp = 0.f;
            float pc[EP], pn[EP];
#pragma unroll
            for (int i = 0; i < EP; ++i) pc[i] = p[i * 64 + lane];
            for (int k = 0; k < NEP; ++k) {
                ANCHOR64(wd);
                const int base = k * EP;
#pragma unroll
                for (int i = 0; i < EP; ++i) {
                    int t = base + EP + i;
                    pn[i] = (t < T) ? p[t * 64 + lane] : 0.f;
                }
                if (base < T) {
#pragma unroll
                    for (int i = 0; i < EP; ++i) {
                        hp = rnn_step_dpp(wd, pc[i], hp, a16, a32, a48);
                        h0ring[(base + i) & (RING - 1)][lane] = hp;
                    }
                }
#pragma unroll
                for (int i = 0; i < EP; ++i) pc[i] = pn[i];
                __syncthreads();
            }
        }
    } else if (wv <= 2) {
        // ---------- helper waves: layer-1 input projection, t-split ----------
        const float* Wih1 = s ? oWih1 : eWih1;
        const float  b1   = s ? (obih1[lane] + obhh1[lane])
                              : (ebih1[lane] + ebhh1[lane]);
        float wi[64];
#pragma unroll
        for (int j = 0; j < 64; ++j) wi[j] = Wih1[lane * 64 + j];

        const int i0 = (wv - 1) * (EP / 2);    // wave1: t 0..3, wave2: t 4..7

        for (int k = 0; k < NEP; ++k) {
            ANCHOR64(wi);
            const int base = k * EP - EP;
            if (base >= 0 && base < T) {
#pragma unroll
                for (int i = 0; i < EP / 2; ++i) {
                    const int t = base + i0 + i;
                    const float4* hv = (const float4*)h0ring[t & (RING - 1)];
                    float q[4] = { b1, 0.f, 0.f, 0.f };
#pragma unroll
                    for (int j4 = 0; j4 < 16; ++j4) {
                        float4 u = hv[j4];
                        q[0] = fmaf(wi[4*j4+0], u.x, q[0]);
                        q[1] = fmaf(wi[4*j4+1], u.y, q[1]);
                        q[2] = fmaf(wi[4*j4+2], u.z, q[2]);
                        q[3] = fmaf(wi[4*j4+3], u.w, q[3]);
                    }
                    qring[t & (RING - 1)][lane] = (q[0] + q[1]) + (q[2] + q[3]);
                }
            }
            __syncthreads();
        }
    } else {
        // ---------- layer-1 recurrence wave ----------
        const float* Whh1 = s ? oWhh1 : eWhh1;
        SelMasks M; build_masks(lo, dirplus, M);
        f16x8 A[4][2];
        load_afrag(Whh1, lo, hi, A);
        const bool useMfma = probe_mfma(Whh1, lane, lo, hi, A, M, pscr[1]);

        if (useMfma) {
            f16x8 bf0 = {}, bf1 = {};
            f32x4 lastTh = {};
            for (int k = 0; k < NEP; ++k) {
                const int base = k * EP - 2 * EP;
                if (base >= 0) {               // base+EP-1 <= T-1 by construction
                    f32x4 qf[2][4];
#pragma unroll
                    for (int b = 0; b < 4; ++b)
                        qf[0][b] = *(const f32x4*)&qring[base & (RING - 1)][16 * b + 4 * hi];
#pragma unroll
                    for (int i = 0; i < EP; ++i) {
                        const int t = base + i;
                        if (i + 1 < EP) {      // all of this epoch published >=1 barrier ago
#pragma unroll
                            for (int b = 0; b < 4; ++b)
                                qf[(i + 1) & 1][b] =
                                    *(const f32x4*)&qring[(t + 1) & (RING - 1)][16 * b + 4 * hi];
                        }
                        f32x4 d[4];
                        mfma8(A, bf0, bf1, qf[i & 1], d);
                        f32x4 th;
                        repack(d, M, bf0, bf1, th);
                        if (t == T - 1) lastTh = th;
                    }
                }
                __syncthreads();
            }
            if (lo < 4)
                *(f32x4*)&hlast[s * 64 + 16 * lo + 4 * hi] = lastTh;
        } else {
            // -------- R7 fallback --------
            float wd[64];
            load_wdpp(Whh1, lane, dirplus, wd);
            float hp = 0.f;
            for (int k = 0; k < NEP; ++k) {
                ANCHOR64(wd);
                const int base = k * EP - 2 * EP;
                if (base >= 0) {
                    float qb[EP];
#pragma unroll
                    for (int i = 0; i < EP; ++i)
                        qb[i] = qring[(base + i) & (RING - 1)][lane];
#pragma unroll
                    for (int i = 0; i < EP; ++i)
                        hp = rnn_step_dpp(wd, qb[i], hp, a16, a32, a48);
                }
                __syncthreads();
            }
            hlast[s * 64 + lane] = hp;
        }
    }
}

// ---------------------------------------------------------------------------
// head: e0 = fce_w@hx + fce_b ; o0 = fco_w@hy + fco_b ; zz=[e0,o0,z];
//       h = relu(fc1_w@zz + fc1_b) ; out = fc2_w@h + fc2_b
// ---------------------------------------------------------------------------
__global__ void head_kernel(const float* __restrict__ hlast,   // [2][64]
                            const float* __restrict__ z,
                            const float* __restrict__ fce_w, const float* __restrict__ fce_b,
                            const float* __restrict__ fco_w, const float* __restrict__ fco_b,
                            const float* __restrict__ fc1_w, const float* __restrict__ fc1_b,
                            const float* __restrict__ fc2_w, const float* __restrict__ fc2_b,
                            float* __restrict__ out)            // [5]
{
    const int lane = threadIdx.x;   // 64 threads
    __shared__ float zz[9];
    __shared__ float hh[64];

    if (lane < 2) {
        float sacc = fce_b[lane];
        for (int j = 0; j < 64; ++j) sacc += fce_w[lane * 64 + j] * hlast[j];
        zz[lane] = sacc;
    } else if (lane < 4) {
        int r = lane - 2;
        float sacc = fco_b[r];
        for (int j = 0; j < 64; ++j) sacc += fco_w[r * 64 + j] * hlast[64 + j];
        zz[lane] = sacc;
    } else if (lane < 9) {
        zz[lane] = z[lane - 4];
    }
    __syncthreads();

    float sacc = fc1_b[lane];
#pragma unroll
    for (int j = 0; j < 9; ++j) sacc += fc1_w[lane * 9 + j] * zz[j];
    hh[lane] = fmaxf(sacc, 0.f);
    __syncthreads();

    if (lane < 5) {
        float o = fc2_b[lane];
        for (int i = 0; i < 64; ++i) o += fc2_w[lane * 64 + i] * hh[i];
        out[lane] = o;
    }
}

// ---------------------------------------------------------------------------
extern "C" void kernel_launch(void* const* d_in, const int* in_sizes, int n_in,
                              void* d_out, int out_size, void* d_ws, size_t ws_size,
                              hipStream_t stream)
{
    const float* x      = (const float*)d_in[0];
    const float* y      = (const float*)d_in[1];
    const float* z      = (const float*)d_in[2];
    const float* e_Wih0 = (const float*)d_in[3];
    const float* e_Whh0 = (const float*)d_in[4];
    const float* e_bih0 = (const float*)d_in[5];
    const float* e_bhh0 = (const float*)d_in[6];
    const float* e_Wih1 = (const float*)d_in[7];
    const float* e_Whh1 = (const float*)d_in[8];
    const float* e_bih1 = (const float*)d_in[9];
    const float* e_bhh1 = (const float*)d_in[10];
    const float* o_Wih0 = (const float*)d_in[11];
    const float* o_Whh0 = (const float*)d_in[12];
    const float* o_bih0 = (const float*)d_in[13];
    const float* o_bhh0 = (const float*)d_in[14];
    const float* o_Wih1 = (const float*)d_in[15];
    const float* o_Whh1 = (const float*)d_in[16];
    const float* o_bih1 = (const float*)d_in[17];
    const float* o_bhh1 = (const float*)d_in[18];
    const float* fce_w  = (const float*)d_in[19];
    const float* fce_b  = (const float*)d_in[20];
    const float* fco_w  = (const float*)d_in[21];
    const float* fco_b  = (const float*)d_in[22];
    const float* fc1_w  = (const float*)d_in[23];
    const float* fc1_b  = (const float*)d_in[24];
    const float* fc2_w  = (const float*)d_in[25];
    const float* fc2_b  = (const float*)d_in[26];

    float* pre   = (float*)d_ws;            // 2*T*64 floats = 2 MB
    float* hlast = pre + 2 * T * 64;        // 128 floats
    float* out   = (float*)d_out;

    prep_kernel<<<(2 * T * 64) / 256, 256, 0, stream>>>(
        x, y, e_Wih0, e_bih0, e_bhh0, o_Wih0, o_bih0, o_bhh0, pre);

    seq_kernel<<<2, 256, 0, stream>>>(
        pre,
        e_Whh0, e_Wih1, e_Whh1, e_bih1, e_bhh1,
        o_Whh0, o_Wih1, o_Whh1, o_bih1, o_bhh1,
        hlast);

    head_kernel<<<1, 64, 0, stream>>>(
        hlast, z, fce_w, fce_b, fco_w, fco_b, fc1_w, fc1_b, fc2_w, fc2_b, out);
}

// Round 13
// 1045.700 us; speedup vs baseline: 1.4533x; 1.4013x over previous
//
#include <hip/hip_runtime.h>

#define T 4096
#define EP 16                     // steps per barrier epoch (R13: halved barrier count)
#define RING 32                   // LDS ring depth (disjoint writer/reader halves mod 32)
#define NEP (T / EP + 2)          // 258 epochs: pipeline depth 2 epochs

// tanh(x) = 1 - 2/(exp(2x)+1). Branch-free, ~1e-6 err.
__device__ __forceinline__ float fast_tanh(float x) {
    float e = __expf(2.0f * x);
    float r = __builtin_amdgcn_rcpf(e + 1.0f);
    return fmaf(-2.0f, r, 1.0f);
}

// 16/64-scalar residency anchors (once per epoch; near-zero cost).
#define ANCHOR16(a, b) asm volatile("" : \
    "+v"((a)[(b)+0]),  "+v"((a)[(b)+1]),  "+v"((a)[(b)+2]),  "+v"((a)[(b)+3]),  \
    "+v"((a)[(b)+4]),  "+v"((a)[(b)+5]),  "+v"((a)[(b)+6]),  "+v"((a)[(b)+7]),  \
    "+v"((a)[(b)+8]),  "+v"((a)[(b)+9]),  "+v"((a)[(b)+10]), "+v"((a)[(b)+11]), \
    "+v"((a)[(b)+12]), "+v"((a)[(b)+13]), "+v"((a)[(b)+14]), "+v"((a)[(b)+15]))
#define ANCHOR64(a) do { ANCHOR16(a, 0); ANCHOR16(a, 16); \
                         ANCHOR16(a, 32); ANCHOR16(a, 48); } while (0)

// ---------------------------------------------------------------------------
// R13: the R7 kernel (verified absmax 0.0, 988 us; best of 6 broadcast
// mechanisms) with ONLY the barrier cadence changed: EP 8->16 (514->258
// barriers). R12 bundled this with an r-domain constant-fold that failed
// numerically; this round unbundles. Products, accumulation order, and load
// values are bit-identical to R7 -> absmax must be 0.0 again.
// Ring safety at EP=16 (mod-32 ring): wave0 writes {16k..16k+15}, helpers
// read {16k-16..16k-1} (disjoint halves); helpers write qring {16k-16..16k-1},
// wave3 reads {16k..16k+15} mod 32 (disjoint). Readers >=1 barrier behind.
// ---------------------------------------------------------------------------
#define ROTF(acc, v, w, R) \
    asm("v_fmac_f32_dpp %0, %1, %2 row_ror:" #R " row_mask:0xf bank_mask:0xf" \
        : "+v"(acc) : "v"(v), "v"(w))

// Hazard-guarded copy: dst is safe as a DPP source for anything sequenced
// after this blob (s_nop 1 = 2 wait states).
#define MOVNOP(dst, src) \
    asm("v_mov_b32 %0, %1\n\ts_nop 1" : "=v"(dst) : "v"(src))

// One 16-rotation block: r=0 plain fma, r=1..15 fused DPP. acc index = r & 3.
#define KBLOCK(v, wd, B) do { \
    a0 = fmaf((v), (wd)[(B) + 0], a0); \
    ROTF(a1, (v), (wd)[(B) + 1],  1);  ROTF(a2, (v), (wd)[(B) + 2],  2); \
    ROTF(a3, (v), (wd)[(B) + 3],  3);  ROTF(a0, (v), (wd)[(B) + 4],  4); \
    ROTF(a1, (v), (wd)[(B) + 5],  5);  ROTF(a2, (v), (wd)[(B) + 6],  6); \
    ROTF(a3, (v), (wd)[(B) + 7],  7);  ROTF(a0, (v), (wd)[(B) + 8],  8); \
    ROTF(a1, (v), (wd)[(B) + 9],  9);  ROTF(a2, (v), (wd)[(B) +10], 10); \
    ROTF(a3, (v), (wd)[(B) +11], 11);  ROTF(a0, (v), (wd)[(B) +12], 12); \
    ROTF(a1, (v), (wd)[(B) +13], 13);  ROTF(a2, (v), (wd)[(B) +14], 14); \
    ROTF(a3, (v), (wd)[(B) +15], 15); \
} while (0)

// One recurrence step (R7, verified absmax 0.0). bpermutes issue first (LDS
// pipe); their latency hides under the k=0 block.
__device__ __forceinline__ float rnn_step_dpp(const float (&wd)[64], float init, float hp,
                                              int a16, int a32, int a48) {
    const int hb = __float_as_int(hp);
    const int b1i = __builtin_amdgcn_ds_bpermute(a16, hb);   // h[i^16]
    const int b2i = __builtin_amdgcn_ds_bpermute(a32, hb);   // h[i^32]
    const int b3i = __builtin_amdgcn_ds_bpermute(a48, hb);   // h[i^48]
    float hpD; MOVNOP(hpD, hp);
    float a0 = init, a1 = 0.f, a2 = 0.f, a3 = 0.f;
    KBLOCK(hpD, wd, 0);
    float v1; MOVNOP(v1, __int_as_float(b1i)); KBLOCK(v1, wd, 16);
    float v2; MOVNOP(v2, __int_as_float(b2i)); KBLOCK(v2, wd, 32);
    float v3; MOVNOP(v3, __int_as_float(b3i)); KBLOCK(v3, wd, 48);
    return fast_tanh((a0 + a1) + (a2 + a3));
}

// Pre-permuted weight row for the DPP decomposition (verified R6/R7, absmax 0).
__device__ __forceinline__ void load_wdpp(const float* __restrict__ W, int lane,
                                          bool dirplus, float (&wd)[64]) {
#pragma unroll
    for (int m = 0; m < 64; ++m) {
        const int k = m >> 4, r = m & 15;
        const int lowoff = dirplus ? r : ((16 - r) & 15);
        const int j = ((lane & 48) | ((lane + lowoff) & 15)) ^ (k << 4);
        wd[m] = W[lane * 64 + j];
    }
}

// ---------------------------------------------------------------------------
// prep: pre[s][t][i] = b_ih0[i] + b_hh0[i] + sum_d W_ih0[i][d] * in[0,t,d]
// Only batch element 0 of x / y matters (reference uses e[0], o[0] only).
// ---------------------------------------------------------------------------
__global__ void prep_kernel(const float* __restrict__ x, const float* __restrict__ y,
                            const float* __restrict__ eW, const float* __restrict__ ebi,
                            const float* __restrict__ ebh,
                            const float* __restrict__ oW, const float* __restrict__ obi,
                            const float* __restrict__ obh,
                            float* __restrict__ pre)
{
    int idx = blockIdx.x * blockDim.x + threadIdx.x;   // 2*T*64 threads
    int i = idx & 63;
    int t = (idx >> 6) & (T - 1);
    int s = idx >> 18;
    const float* in = s ? y : x;          // batch 0 = first T*3 floats
    const float* W  = s ? oW : eW;        // [64][3]
    const float* bi = s ? obi : ebi;
    const float* bh = s ? obh : ebh;
    float v = bi[i] + bh[i]
            + W[i*3+0]*in[t*3+0] + W[i*3+1]*in[t*3+1] + W[i*3+2]*in[t*3+2];
    pre[idx] = v;
}

// ---------------------------------------------------------------------------
// seq: grid=2 (one block per RNN), 4 specialized waves, barrier per EP epoch.
//   wave0 @ epoch k: h0[t] = tanh(p[t] + Whh0@h0[t-1]), t in [16k, 16k+16)
//   wave1/wave2 @ epoch k: q[t] = b1 + Wih1@h0[t], t-split halves of [16k-16,16k)
//   wave3 @ epoch k: h1[t] = tanh(q[t] + Whh1@h1[t-1]), t in [16k-32, 16k-16)
// ---------------------------------------------------------------------------
__global__ __launch_bounds__(256, 1) void seq_kernel(
    const float* __restrict__ pre,            // [2][T][64]
    const float* __restrict__ eWhh0, const float* __restrict__ eWih1,
    const float* __restrict__ eWhh1, const float* __restrict__ ebih1,
    const float* __restrict__ ebhh1,
    const float* __restrict__ oWhh0, const float* __restrict__ oWih1,
    const float* __restrict__ oWhh1, const float* __restrict__ obih1,
    const float* __restrict__ obhh1,
    float* __restrict__ hlast)                // [2][64]
{
    const int s    = blockIdx.x;
    const int wv   = threadIdx.x >> 6;
    const int lane = threadIdx.x & 63;

    __shared__ __align__(16) float h0ring[RING][64];
    __shared__ __align__(16) float qring[RING][64];

    const float* p = pre + s * T * 64;

    // Probe the hardware row_ror direction (wave-uniform result; R6-verified).
    const int got = __builtin_amdgcn_update_dpp(0, lane, 0x121, 0xF, 0xF, false);
    const bool dirplus = ((got & 15) == ((lane + 1) & 15));
    // bpermute byte-addresses for the three XOR-copies
    const int a16 = (lane ^ 16) << 2;
    const int a32 = (lane ^ 32) << 2;
    const int a48 = (lane ^ 48) << 2;

    if (wv == 0) {
        // ---------- layer-0 recurrence wave ----------
        const float* Whh0 = s ? oWhh0 : eWhh0;
        float wd[64];
        load_wdpp(Whh0, lane, dirplus, wd);

        float hp = 0.f;                        // h0[t-1]
        float pc[EP], pn[EP];
#pragma unroll
        for (int i = 0; i < EP; ++i) pc[i] = p[i * 64 + lane];

        for (int k = 0; k < NEP; ++k) {
            ANCHOR64(wd);                      // keep weight row resident
            const int base = k * EP;
            // prefetch next epoch's p (consumed next epoch -> latency hidden)
#pragma unroll
            for (int i = 0; i < EP; ++i) {
                int t = base + EP + i;
                pn[i] = (t < T) ? p[t * 64 + lane] : 0.f;
            }
            if (base < T) {                    // wave-uniform scalar branch
#pragma unroll
                for (int i = 0; i < EP; ++i) {
                    hp = rnn_step_dpp(wd, pc[i], hp, a16, a32, a48);
                    h0ring[(base + i) & (RING - 1)][lane] = hp;   // publish
                }
            }
#pragma unroll
            for (int i = 0; i < EP; ++i) pc[i] = pn[i];
            __syncthreads();
        }
    } else if (wv <= 2) {
        // ---------- helper waves: layer-1 input projection, t-split ----------
        const float* Wih1 = s ? oWih1 : eWih1;
        const float  b1   = s ? (obih1[lane] + obhh1[lane])
                              : (ebih1[lane] + ebhh1[lane]);
        float wi[64];
#pragma unroll
        for (int j = 0; j < 64; ++j) wi[j] = Wih1[lane * 64 + j];

        const int i0 = (wv - 1) * (EP / 2);    // wave1: t 0..7, wave2: t 8..15

        for (int k = 0; k < NEP; ++k) {
            ANCHOR64(wi);
            const int base = k * EP - EP;
            if (base >= 0 && base < T) {
#pragma unroll
                for (int i = 0; i < EP / 2; ++i) {
                    const int t = base + i0 + i;
                    const float4* hv = (const float4*)h0ring[t & (RING - 1)];
                    float q[4] = { b1, 0.f, 0.f, 0.f };
#pragma unroll
                    for (int j4 = 0; j4 < 16; ++j4) {
                        float4 u = hv[j4];
                        q[0] = fmaf(wi[4*j4+0], u.x, q[0]);
                        q[1] = fmaf(wi[4*j4+1], u.y, q[1]);
                        q[2] = fmaf(wi[4*j4+2], u.z, q[2]);
                        q[3] = fmaf(wi[4*j4+3], u.w, q[3]);
                    }
                    qring[t & (RING - 1)][lane] = (q[0] + q[1]) + (q[2] + q[3]);
                }
            }
            __syncthreads();
        }
    } else {
        // ---------- layer-1 recurrence wave ----------
        const float* Whh1 = s ? oWhh1 : eWhh1;
        float wd[64];
        load_wdpp(Whh1, lane, dirplus, wd);

        float hp = 0.f;                        // h1[t-1]
        for (int k = 0; k < NEP; ++k) {
            ANCHOR64(wd);
            const int base = k * EP - 2 * EP;
            if (base >= 0) {                   // base+EP-1 <= T-1 by construction
                float qb[EP];
#pragma unroll
                for (int i = 0; i < EP; ++i)   // all written >=1 epoch ago
                    qb[i] = qring[(base + i) & (RING - 1)][lane];
#pragma unroll
                for (int i = 0; i < EP; ++i)
                    hp = rnn_step_dpp(wd, qb[i], hp, a16, a32, a48);
            }
            __syncthreads();
        }
        hlast[s * 64 + lane] = hp;             // h1[T-1]
    }
}

// ---------------------------------------------------------------------------
// head: e0 = fce_w@hx + fce_b ; o0 = fco_w@hy + fco_b ; zz=[e0,o0,z];
//       h = relu(fc1_w@zz + fc1_b) ; out = fc2_w@h + fc2_b
// ---------------------------------------------------------------------------
__global__ void head_kernel(const float* __restrict__ hlast,   // [2][64]
                            const float* __restrict__ z,
                            const float* __restrict__ fce_w, const float* __restrict__ fce_b,
                            const float* __restrict__ fco_w, const float* __restrict__ fco_b,
                            const float* __restrict__ fc1_w, const float* __restrict__ fc1_b,
                            const float* __restrict__ fc2_w, const float* __restrict__ fc2_b,
                            float* __restrict__ out)            // [5]
{
    const int lane = threadIdx.x;   // 64 threads
    __shared__ float zz[9];
    __shared__ float hh[64];

    if (lane < 2) {
        float sacc = fce_b[lane];
        for (int j = 0; j < 64; ++j) sacc += fce_w[lane * 64 + j] * hlast[j];
        zz[lane] = sacc;
    } else if (lane < 4) {
        int r = lane - 2;
        float sacc = fco_b[r];
        for (int j = 0; j < 64; ++j) sacc += fco_w[r * 64 + j] * hlast[64 + j];
        zz[lane] = sacc;
    } else if (lane < 9) {
        zz[lane] = z[lane - 4];
    }
    __syncthreads();

    float sacc = fc1_b[lane];
#pragma unroll
    for (int j = 0; j < 9; ++j) sacc += fc1_w[lane * 9 + j] * zz[j];
    hh[lane] = fmaxf(sacc, 0.f);
    __syncthreads();

    if (lane < 5) {
        float o = fc2_b[lane];
        for (int i = 0; i < 64; ++i) o += fc2_w[lane * 64 + i] * hh[i];
        out[lane] = o;
    }
}

// ---------------------------------------------------------------------------
extern "C" void kernel_launch(void* const* d_in, const int* in_sizes, int n_in,
                              void* d_out, int out_size, void* d_ws, size_t ws_size,
                              hipStream_t stream)
{
    const float* x      = (const float*)d_in[0];
    const float* y      = (const float*)d_in[1];
    const float* z      = (const float*)d_in[2];
    const float* e_Wih0 = (const float*)d_in[3];
    const float* e_Whh0 = (const float*)d_in[4];
    const float* e_bih0 = (const float*)d_in[5];
    const float* e_bhh0 = (const float*)d_in[6];
    const float* e_Wih1 = (const float*)d_in[7];
    const float* e_Whh1 = (const float*)d_in[8];
    const float* e_bih1 = (const float*)d_in[9];
    const float* e_bhh1 = (const float*)d_in[10];
    const float* o_Wih0 = (const float*)d_in[11];
    const float* o_Whh0 = (const float*)d_in[12];
    const float* o_bih0 = (const float*)d_in[13];
    const float* o_bhh0 = (const float*)d_in[14];
    const float* o_Wih1 = (const float*)d_in[15];
    const float* o_Whh1 = (const float*)d_in[16];
    const float* o_bih1 = (const float*)d_in[17];
    const float* o_bhh1 = (const float*)d_in[18];
    const float* fce_w  = (const float*)d_in[19];
    const float* fce_b  = (const float*)d_in[20];
    const float* fco_w  = (const float*)d_in[21];
    const float* fco_b  = (const float*)d_in[22];
    const float* fc1_w  = (const float*)d_in[23];
    const float* fc1_b  = (const float*)d_in[24];
    const float* fc2_w  = (const float*)d_in[25];
    const float* fc2_b  = (const float*)d_in[26];

    float* pre   = (float*)d_ws;            // 2*T*64 floats = 2 MB
    float* hlast = pre + 2 * T * 64;        // 128 floats
    float* out   = (float*)d_out;

    prep_kernel<<<(2 * T * 64) / 256, 256, 0, stream>>>(
        x, y, e_Wih0, e_bih0, e_bhh0, o_Wih0, o_bih0, o_bhh0, pre);

    seq_kernel<<<2, 256, 0, stream>>>(
        pre,
        e_Whh0, e_Wih1, e_Whh1, e_bih1, e_bhh1,
        o_Whh0, o_Wih1, o_Whh1, o_bih1, o_bhh1,
        hlast);

    head_kernel<<<1, 64, 0, stream>>>(
        hlast, z, fce_w, fce_b, fco_w, fco_b, fc1_w, fc1_b, fc2_w, fc2_b, out);
}